// Round 2
// baseline (1413.533 us; speedup 1.0000x reference)
//
#include <hip/hip_runtime.h>

// NeuralVoxelHash: out[i] = sum over 3 levels of trilinear-weighted gather of
// hashed voxel-corner features.
//
// inputs (harness delivers integer inputs as int32!):
//   d_in[0] query_points [1000000,3] f32
//   d_in[1] features     [3,4194304,8] f32
//   d_in[2] index_table  [3,5000000] int32  (reference int64, harness -> int)
// output: [1000000,8] f32

constexpr int       BUF   = 5000000;
constexpr long long NFEAT = 4194304;
constexpr int       DIM   = 8;
constexpr long long P0 = 73856093, P1 = 19349669, P2 = 83492791;

__global__ __launch_bounds__(256) void nvh_kernel(
    const float* __restrict__ qp,
    const float* __restrict__ feats,
    const int* __restrict__ idx_tab,
    float* __restrict__ out, int n)
{
    int i = blockIdx.x * blockDim.x + threadIdx.x;
    if (i >= n) return;

    const float px = qp[3 * i + 0];
    const float py = qp[3 * i + 1];
    const float pz = qp[3 * i + 2];

    float acc[DIM];
#pragma unroll
    for (int d = 0; d < DIM; ++d) acc[d] = 0.0f;

    const float resv[3] = {0.3f, 0.6f, 1.2f};

#pragma unroll
    for (int lvl = 0; lvl < 3; ++lvl) {
        const float res = resv[lvl];
        // IEEE f32 division to match JAX exactly (floor() boundary sensitivity)
        const float fx = px / res, fy = py / res, fz = pz / res;
        const float bx = floorf(fx), by = floorf(fy), bz = floorf(fz);
        const float dx = fx - bx, dy = fy - by, dz = fz - bz;

        const long long ix = (long long)bx;
        const long long iy = (long long)by;
        const long long iz = (long long)bz;

        // one 64-bit floor-mod per level; corner deltas are compile-time consts
        long long h0 = (ix * P0 + iy * P1 + iz * P2) % (long long)BUF;
        if (h0 < 0) h0 += BUF;
        const int k0 = (int)h0;  // [0, BUF)

        const int*   tab = idx_tab + (long long)lvl * BUF;
        const float* fb  = feats + (size_t)lvl * (size_t)NFEAT * DIM;

        // gather 8 corner indices (issue all loads before use for MLP)
        int idxv[8];
#pragma unroll
        for (int c = 0; c < 8; ++c) {
            const long long offc = (((c >> 2) & 1) * P0 + ((c >> 1) & 1) * P1 +
                                    (c & 1) * P2) % (long long)BUF;  // const-folded
            int k = k0 + (int)offc;
            if (k >= BUF) k -= BUF;
            idxv[c] = tab[k];
        }

        bool valid = true;
#pragma unroll
        for (int c = 0; c < 8; ++c) valid = valid && (idxv[c] > -1);

        const float wx1 = dx, wx0 = 1.0f - dx;
        const float wy1 = dy, wy0 = 1.0f - dy;
        const float wz1 = dz, wz0 = 1.0f - dz;

        float lacc[DIM];
#pragma unroll
        for (int d = 0; d < DIM; ++d) lacc[d] = 0.0f;

#pragma unroll
        for (int c = 0; c < 8; ++c) {
            const float wc = (((c >> 2) & 1) ? wx1 : wx0) *
                             (((c >> 1) & 1) ? wy1 : wy0) *
                             (((c     ) & 1) ? wz1 : wz0);
            int id = idxv[c] > 0 ? idxv[c] : 0;  // max(idx, 0)
            const float4* fp = (const float4*)(fb + (size_t)id * DIM);
            const float4 f0 = fp[0];
            const float4 f1 = fp[1];
            lacc[0] += wc * f0.x; lacc[1] += wc * f0.y;
            lacc[2] += wc * f0.z; lacc[3] += wc * f0.w;
            lacc[4] += wc * f1.x; lacc[5] += wc * f1.y;
            lacc[6] += wc * f1.z; lacc[7] += wc * f1.w;
        }

        if (valid) {
#pragma unroll
            for (int d = 0; d < DIM; ++d) acc[d] += lacc[d];
        }
    }

    float4* op = (float4*)(out + (size_t)i * DIM);
    op[0] = make_float4(acc[0], acc[1], acc[2], acc[3]);
    op[1] = make_float4(acc[4], acc[5], acc[6], acc[7]);
}

extern "C" void kernel_launch(void* const* d_in, const int* in_sizes, int n_in,
                              void* d_out, int out_size, void* d_ws, size_t ws_size,
                              hipStream_t stream) {
    const float* qp      = (const float*)d_in[0];
    const float* feats   = (const float*)d_in[1];
    const int*   idx_tab = (const int*)d_in[2];
    float*       out     = (float*)d_out;

    const int n = in_sizes[0] / 3;
    const int block = 256;
    const int grid = (n + block - 1) / block;
    hipLaunchKernelGGL(nvh_kernel, dim3(grid), dim3(block), 0, stream,
                       qp, feats, idx_tab, out, n);
}